// Round 1
// baseline (227.803 us; speedup 1.0000x reference)
//
#include <hip/hip_runtime.h>
#include <stdint.h>

#define HT_STRIDE 262144   // 4096*64 elements per head

typedef __attribute__((ext_vector_type(8))) short bf16x8;
typedef __attribute__((ext_vector_type(4))) float f32x4;

__device__ __forceinline__ unsigned short f2bf(float f) {
    unsigned int u = __float_as_uint(f);
    u += 0x7FFFu + ((u >> 16) & 1u);
    return (unsigned short)(u >> 16);
}

// ---------------------------------------------------------------------------
// Kernel A: ht = h(4096x128) @ W(128x512), f32 in, f32 out, into d_out.
// ---------------------------------------------------------------------------
__global__ void __launch_bounds__(256) k_linear(const float* __restrict__ h,
                                                const float* __restrict__ W,
                                                float* __restrict__ ht) {
    __shared__ float hs[8][128];
    const int t = threadIdx.x;
    const int n0 = blockIdx.x * 8;
    {
        float4 v = ((const float4*)(h + n0 * 128))[t];
        int e = t * 4;
        int r = e >> 7, f = e & 127;
        hs[r][f + 0] = v.x; hs[r][f + 1] = v.y;
        hs[r][f + 2] = v.z; hs[r][f + 3] = v.w;
    }
    __syncthreads();
    float acc0[8], acc1[8];
    #pragma unroll
    for (int r = 0; r < 8; ++r) { acc0[r] = 0.f; acc1[r] = 0.f; }
    const float2* Wf = (const float2*)W;
    for (int f = 0; f < 128; ++f) {
        float2 wp = Wf[f * 256 + t];
        #pragma unroll
        for (int r = 0; r < 8; ++r) {
            float hv = hs[r][f];
            acc0[r] = fmaf(hv, wp.x, acc0[r]);
            acc1[r] = fmaf(hv, wp.y, acc1[r]);
        }
    }
    float2* ob = (float2*)ht;
    #pragma unroll
    for (int r = 0; r < 8; ++r) {
        ob[(n0 + r) * 256 + t] = make_float2(acc0[r], acc1[r]);
    }
}

// ---------------------------------------------------------------------------
// Kernel A2: htT2[hd][m>>5][o][m&31] = bf16(ht[hd][m][o])   (k-tiled layout)
// ---------------------------------------------------------------------------
__global__ void __launch_bounds__(256) k_transpose(const float* __restrict__ ht,
                                                   unsigned short* __restrict__ htT2) {
    __shared__ unsigned short tile[64][65];   // [m_local][o]
    const int t = threadIdx.x;
    const int hd = blockIdx.x >> 6;
    const int m0 = (blockIdx.x & 63) * 64;
    const float* s = ht + hd * HT_STRIDE + m0 * 64;
    #pragma unroll
    for (int i = 0; i < 16; ++i) {
        int idx = t + 256 * i;                // m_local*64 + o
        tile[idx >> 6][idx & 63] = f2bf(s[idx]);
    }
    __syncthreads();
    unsigned short* d = htT2 + hd * HT_STRIDE + (m0 >> 5) * 2048;
    #pragma unroll
    for (int i = 0; i < 16; ++i) {
        int idx = t + 256 * i;                // o*64 + mi
        int o = idx >> 6, mi = idx & 63;
        d[(mi >> 5) * 2048 + o * 32 + (mi & 31)] = tile[mi][o];
    }
}

// ---------------------------------------------------------------------------
// Kernel B: src/tgt projections. One wave per (head, node).
// ---------------------------------------------------------------------------
__global__ void __launch_bounds__(256) k_srctgt(const float* __restrict__ ht,
                                                const float* __restrict__ aW,
                                                float* __restrict__ src,
                                                float* __restrict__ tgt) {
    const int t = threadIdx.x;
    const int p = blockIdx.x * 4 + (t >> 6);
    const int lane = t & 63;
    const int hd = p >> 12;
    float hv = ht[p * 64 + lane];
    float a1 = aW[hd * 128 + lane];
    float a2 = aW[hd * 128 + 64 + lane];
    float s = hv * a1, g = hv * a2;
    #pragma unroll
    for (int off = 32; off > 0; off >>= 1) {
        s += __shfl_down(s, off, 64);
        g += __shfl_down(g, off, 64);
    }
    if (lane == 0) { src[p] = s; tgt[p] = g; }
}

// ---------------------------------------------------------------------------
// Kernel C: tmax[hd] = max_m tgt[hd][m]
// ---------------------------------------------------------------------------
__global__ void __launch_bounds__(256) k_tgtmax(const float* __restrict__ tgt,
                                                float* __restrict__ tmax) {
    __shared__ float red[256];
    const int t = threadIdx.x;
    const int hd = blockIdx.x;
    float m = -1e30f;
    for (int i = t; i < 4096; i += 256) m = fmaxf(m, tgt[hd * 4096 + i]);
    red[t] = m;
    __syncthreads();
    for (int s2 = 128; s2 > 0; s2 >>= 1) {
        if (t < s2) red[t] = fmaxf(red[t], red[t + s2]);
        __syncthreads();
    }
    if (t == 0) tmax[hd] = red[0];
}

// ---------------------------------------------------------------------------
// Kernel D v3: fused GAT attention.
// grid 512 x 1024 thr: block = (16-row stripe, 4-head group); 16 waves =
// 4 heads x 4 k-quarters -> 8192 total waves = 32 waves/CU (2 blocks/CU,
// forced by __launch_bounds__(1024,8) + 69.7 KB LDS).
// stripe = bid&255, hg = bid>>8 so the two blocks sharing a stripe map to the
// same XCD (bid ≡ bid+256 mod 8) -> duplicated adjacency read is an L2 hit.
// Per c-iter VALU diet: lrelu/max-sub fold (add,fma,max,mul,exp per elem),
// v_cvt_pk_bf16_f32 packing (4 instr replaces ~40), no manual prefetch
// (latency hidden by 8 waves/SIMD; exp block sits between A-frag loads and
// their MFMA consumers).
// ---------------------------------------------------------------------------
__global__ void __launch_bounds__(1024, 8) k_attn(const int* __restrict__ adj,
                                                  const unsigned short* __restrict__ htT2,
                                                  const float* __restrict__ src,
                                                  const float* __restrict__ tgt,
                                                  const float* __restrict__ tmax,
                                                  float* __restrict__ out) {
    __shared__ unsigned int bm[16 * 129];                 // 16 rows x 128 words, +1 pad
    __shared__ __align__(16) float comb[3][4][64][20];    // kq 1..3 partials (+pd at [16])

    const int t = threadIdx.x;
    const int wave = t >> 6;                  // 0..15
    const int lane = t & 63;
    const int hs = wave >> 2;                 // head-sub 0..3
    const int kq = wave & 3;                  // k-quarter 0..3
    const int li = lane & 15;
    const int quad = lane >> 4;
    const int stripe = blockIdx.x & 255;
    const int hg = blockIdx.x >> 8;
    const int head = (hg << 2) + hs;
    const int i0 = stripe * 16;

    // ---- Phase 1: adjacency bitmask (wave w builds row w) ----
    {
        const int* arow = adj + (i0 + wave) * 4096;
        #pragma unroll 4
        for (int s = 0; s < 64; ++s) {
            int v = arow[s * 64 + lane];
            unsigned long long m = __ballot(v > 0);
            if (lane < 2) bm[wave * 129 + 2 * s + lane] = (unsigned int)(m >> (lane * 32));
        }
    }
    __syncthreads();

    // ---- Phase 2: main loop over this wave's k-quarter (32 c-iters) ----
    const float sv = src[head * 4096 + i0 + li];
    const float tm0 = sv + tmax[head];
    const float mi = fmaxf(tm0, 0.2f * tm0);  // lrelu(src+max tgt) >= row max
    const float c1 = sv - mi;                 // t1 = tt + c1
    const float c2 = fmaf(0.2f, sv, -mi);     // t2 = 0.2*tt + c2

    f32x4 acc[4];
    #pragma unroll
    for (int f = 0; f < 4; ++f) acc[f] = (f32x4){0.f, 0.f, 0.f, 0.f};
    float pd = 0.f;

    const unsigned int* bmr = bm + li * 129;
    const float4* tgtp = (const float4*)(tgt + head * 4096);
    const uint4*  ap   = (const uint4*)(htT2 + head * HT_STRIDE) + (li * 4 + quad);

    const int c0 = kq * 32;
    #pragma unroll 1
    for (int c = c0; c < c0 + 32; ++c) {
        // issue A-frag loads first; exp block below hides their latency
        const uint4* apc = ap + c * 256;
        uint4 av0 = apc[0];
        uint4 av1 = apc[64];
        uint4 av2 = apc[128];
        uint4 av3 = apc[192];
        float4 tg0 = tgtp[c * 8 + quad * 2 + 0];
        float4 tg1 = tgtp[c * 8 + quad * 2 + 1];
        unsigned int wq = bmr[c] >> (quad * 8);

        const float tt[8] = {tg0.x, tg0.y, tg0.z, tg0.w, tg1.x, tg1.y, tg1.z, tg1.w};
        float wv[8];
        #pragma unroll
        for (int j = 0; j < 8; ++j) {
            float t1 = tt[j] + c1;                  // (sv+tt) - mi
            float t2 = fmaf(tt[j], 0.2f, c2);       // 0.2*(sv+tt) - mi
            float e = fmaxf(t1, t2);                // lrelu(sv+tt) - mi  (<= 0)
            float p = __expf(e);
            wv[j] = ((wq >> j) & 1u) ? p : 0.f;
            pd += wv[j];
        }

        unsigned int pk0, pk1, pk2, pk3;
        asm("v_cvt_pk_bf16_f32 %0, %1, %2" : "=v"(pk0) : "v"(wv[0]), "v"(wv[1]));
        asm("v_cvt_pk_bf16_f32 %0, %1, %2" : "=v"(pk1) : "v"(wv[2]), "v"(wv[3]));
        asm("v_cvt_pk_bf16_f32 %0, %1, %2" : "=v"(pk2) : "v"(wv[4]), "v"(wv[5]));
        asm("v_cvt_pk_bf16_f32 %0, %1, %2" : "=v"(pk3) : "v"(wv[6]), "v"(wv[7]));
        uint4 bv; bv.x = pk0; bv.y = pk1; bv.z = pk2; bv.w = pk3;
        bf16x8 bfrag = __builtin_bit_cast(bf16x8, bv);

        acc[0] = __builtin_amdgcn_mfma_f32_16x16x32_bf16(__builtin_bit_cast(bf16x8, av0), bfrag, acc[0], 0, 0, 0);
        acc[1] = __builtin_amdgcn_mfma_f32_16x16x32_bf16(__builtin_bit_cast(bf16x8, av1), bfrag, acc[1], 0, 0, 0);
        acc[2] = __builtin_amdgcn_mfma_f32_16x16x32_bf16(__builtin_bit_cast(bf16x8, av2), bfrag, acc[2], 0, 0, 0);
        acc[3] = __builtin_amdgcn_mfma_f32_16x16x32_bf16(__builtin_bit_cast(bf16x8, av3), bfrag, acc[3], 0, 0, 0);
    }

    // ---- Phase 3: combine the 4 k-quarters, denominator, store ----
    if (kq != 0) {
        f32x4* cb = (f32x4*)&comb[kq - 1][hs][lane][0];
        #pragma unroll
        for (int f = 0; f < 4; ++f) cb[f] = acc[f];
        comb[kq - 1][hs][lane][16] = pd;
    }
    __syncthreads();
    if (kq == 0) {
        #pragma unroll
        for (int q = 0; q < 3; ++q) {
            const f32x4* cb = (const f32x4*)&comb[q][hs][lane][0];
            #pragma unroll
            for (int f = 0; f < 4; ++f) acc[f] += cb[f];
            pd += comb[q][hs][lane][16];
        }
        pd += __shfl_xor(pd, 16, 64);
        pd += __shfl_xor(pd, 32, 64);
        const float rd = 1.0f / pd;

        float4* op = (float4*)(out + head * HT_STRIDE + (i0 + li) * 64);
        #pragma unroll
        for (int f = 0; f < 4; ++f) {
            op[f * 4 + quad] = make_float4(acc[f][0] * rd, acc[f][1] * rd,
                                           acc[f][2] * rd, acc[f][3] * rd);
        }
    }
}

extern "C" void kernel_launch(void* const* d_in, const int* in_sizes, int n_in,
                              void* d_out, int out_size, void* d_ws, size_t ws_size,
                              hipStream_t stream) {
    const float* h   = (const float*)d_in[0];  // (1,4096,128) f32
    const int*   adj = (const int*)d_in[1];    // (4096,4096) i32
    const float* W   = (const float*)d_in[2];  // (128,512) f32
    const float* aW  = (const float*)d_in[3];  // (8,128,1) f32
    float* out = (float*)d_out;                // (1,8,4096,64) f32

    // ws layout (~4.26 MB, proven safe): src | tgt | tmax | htT2(bf16, k-tiled)
    char* ws = (char*)d_ws;
    float* src  = (float*)(ws);
    float* tgt  = (float*)(ws + 131072);
    float* tmax = (float*)(ws + 262144);
    unsigned short* htT2 = (unsigned short*)(ws + 266240);
    float* ht = out;   // ht (f32) lives in d_out; k_attn overwrites it last

    hipLaunchKernelGGL(k_linear,    dim3(512),  dim3(256),  0, stream, h, W, ht);
    hipLaunchKernelGGL(k_srctgt,    dim3(8192), dim3(256),  0, stream, ht, aW, src, tgt);
    hipLaunchKernelGGL(k_tgtmax,    dim3(8),    dim3(256),  0, stream, tgt, tmax);
    hipLaunchKernelGGL(k_transpose, dim3(512),  dim3(256),  0, stream, ht, htT2);
    hipLaunchKernelGGL(k_attn,      dim3(512),  dim3(1024), 0, stream, adj, htT2, src, tgt, tmax, out);
}

// Round 2
// 177.097 us; speedup vs baseline: 1.2863x; 1.2863x over previous
//
#include <hip/hip_runtime.h>
#include <stdint.h>

#define HT_STRIDE 262144   // 4096*64 elements per head

typedef __attribute__((ext_vector_type(8))) short bf16x8;
typedef __attribute__((ext_vector_type(4))) float f32x4;

__device__ __forceinline__ unsigned short f2bf(float f) {
    unsigned int u = __float_as_uint(f);
    u += 0x7FFFu + ((u >> 16) & 1u);
    return (unsigned short)(u >> 16);
}

// ---------------------------------------------------------------------------
// Kernel A: ht = h(4096x128) @ W(128x512), f32 in, f32 out, into d_out.
// ---------------------------------------------------------------------------
__global__ void __launch_bounds__(256) k_linear(const float* __restrict__ h,
                                                const float* __restrict__ W,
                                                float* __restrict__ ht) {
    __shared__ float hs[8][128];
    const int t = threadIdx.x;
    const int n0 = blockIdx.x * 8;
    {
        float4 v = ((const float4*)(h + n0 * 128))[t];
        int e = t * 4;
        int r = e >> 7, f = e & 127;
        hs[r][f + 0] = v.x; hs[r][f + 1] = v.y;
        hs[r][f + 2] = v.z; hs[r][f + 3] = v.w;
    }
    __syncthreads();
    float acc0[8], acc1[8];
    #pragma unroll
    for (int r = 0; r < 8; ++r) { acc0[r] = 0.f; acc1[r] = 0.f; }
    const float2* Wf = (const float2*)W;
    for (int f = 0; f < 128; ++f) {
        float2 wp = Wf[f * 256 + t];
        #pragma unroll
        for (int r = 0; r < 8; ++r) {
            float hv = hs[r][f];
            acc0[r] = fmaf(hv, wp.x, acc0[r]);
            acc1[r] = fmaf(hv, wp.y, acc1[r]);
        }
    }
    float2* ob = (float2*)ht;
    #pragma unroll
    for (int r = 0; r < 8; ++r) {
        ob[(n0 + r) * 256 + t] = make_float2(acc0[r], acc1[r]);
    }
}

// ---------------------------------------------------------------------------
// Kernel B (fused prep): per 64-row p-chunk of ht (flat [32768][64] view):
//   - src/tgt projections (replaces k_srctgt)
//   - bf16 k-tiled transpose htT2[hd][m>>5][o][m&31] (replaces k_transpose)
// tgtmax is dropped: |lrelu(src+tgt)| <= ~8, f32 exp is safe unshifted.
// ---------------------------------------------------------------------------
__global__ void __launch_bounds__(256) k_prep(const float* __restrict__ ht,
                                              const float* __restrict__ aW,
                                              float* __restrict__ src,
                                              float* __restrict__ tgt,
                                              unsigned short* __restrict__ htT2) {
    __shared__ float ldsA[64][65];
    __shared__ float redS[4][64];
    __shared__ float redT[4][64];
    const int t = threadIdx.x;
    const int p0 = blockIdx.x * 64;        // 64 | 4096 -> never spans heads
    const int hd = p0 >> 12;
    const int m0 = p0 & 4095;

    // stage 64x64 f32 tile, coalesced
    {
        const float4* g = (const float4*)(ht + p0 * 64);
        #pragma unroll
        for (int i = 0; i < 4; ++i) {
            int fid = t + 256 * i;
            float4 v = g[fid];
            int r = fid >> 4, o4 = (fid & 15) * 4;
            ldsA[r][o4 + 0] = v.x; ldsA[r][o4 + 1] = v.y;
            ldsA[r][o4 + 2] = v.z; ldsA[r][o4 + 3] = v.w;
        }
    }
    __syncthreads();

    // src/tgt partial dots: thread t handles (row = t&63, o-range (t>>6)*16)
    {
        const int r = t & 63, og = t >> 6;
        float s = 0.f, g2 = 0.f;
        #pragma unroll
        for (int k = 0; k < 16; ++k) {
            int o = og * 16 + k;
            float hv = ldsA[r][o];
            s  = fmaf(hv, aW[hd * 128 + o], s);
            g2 = fmaf(hv, aW[hd * 128 + 64 + o], g2);
        }
        redS[og][r] = s; redT[og][r] = g2;
    }
    __syncthreads();
    if (t < 64) {
        src[p0 + t] = redS[0][t] + redS[1][t] + redS[2][t] + redS[3][t];
    } else if (t < 128) {
        int r = t - 64;
        tgt[p0 + r] = redT[0][r] + redT[1][r] + redT[2][r] + redT[3][r];
    }

    // bf16 k-tiled transpose out (contiguous 8 KB per block)
    unsigned short* d = htT2 + (hd * 128 + (m0 >> 5)) * 2048;
    #pragma unroll
    for (int i = 0; i < 16; ++i) {
        int id = t + 256 * i;
        int mi = id & 31, o = (id >> 5) & 63, ct = id >> 11;
        d[ct * 2048 + o * 32 + mi] = f2bf(ldsA[mi + 32 * ct][o]);
    }
}

// ---------------------------------------------------------------------------
// Kernel C: adjacency (64 MB, read ONCE at HBM rate) -> 2 MB bitmask.
// Layout matches k_attn LDS: abm[stripe][c 128][li 16][g 4] words,
// word(c) bit k = adj[stripe*64 + 16g + li][32c + k].
// Block = (stripe s, 512-col slice cq); wave w handles rows w*16..+15 (g=w).
// ---------------------------------------------------------------------------
__global__ void __launch_bounds__(256) k_adjmask(const int* __restrict__ adj,
                                                 unsigned int* __restrict__ abm) {
    __shared__ unsigned int ldsT[1024];
    const int t = threadIdx.x;
    const int lane = t & 63;
    const int w = t >> 6;
    const int s = blockIdx.x >> 3;
    const int cq = blockIdx.x & 7;
    for (int rr = 0; rr < 16; ++rr) {
        const int* arow = adj + (s * 64 + w * 16 + rr) * 4096 + cq * 512;
        int v[8];
        #pragma unroll
        for (int j = 0; j < 8; ++j) v[j] = arow[j * 64 + lane];
        #pragma unroll
        for (int j = 0; j < 8; ++j) {
            unsigned long long m = __ballot(v[j] > 0);
            if (lane < 2)
                ldsT[(2 * j + lane) * 64 + rr * 4 + w] = (unsigned int)(m >> (lane * 32));
        }
    }
    __syncthreads();
    ((uint4*)(abm + (s * 128 + cq * 16) * 64))[t] = ((uint4*)ldsT)[t];
}

// ---------------------------------------------------------------------------
// Kernel D v4: fused GAT attention, traffic-optimized.
// grid 512 x 256 thr: block = (head = bid&7, stripe of 64 rows = bid>>3).
//   head == bid%8 == XCD -> each XCD touches only its 512 KB htT2 slice
//   (+2 MB bitmask) -> A-frags L2-resident, never L3 (round-1 bottleneck).
// 4 waves = 4 k-quarters; each wave: 64 rows (li + 16g, g=0..3) x 32 c-iters.
// Per c-iter: 1 ds_read_b128 (bitmask) + 4 uint4 A-frags (reused by 4 row
// groups -> A-traffic 1 GB -> 256 MB) + 2 broadcast float4 tgt + 32 exp +
// 16 cvt_pk + 16 MFMA. Next-iter register prefetch. acc = 64 AGPRs.
// LDS union: bitmask tile (32 KB) then kq-combine buffer (52 KB).
// ---------------------------------------------------------------------------
__global__ void __launch_bounds__(256, 2) k_attn(const unsigned int* __restrict__ abm,
                                                 const unsigned short* __restrict__ htT2,
                                                 const float* __restrict__ srcv,
                                                 const float* __restrict__ tgtv,
                                                 float* __restrict__ out) {
    __shared__ __align__(16) float smem[13056];   // 52224 B union
    unsigned int* bm = (unsigned int*)smem;

    const int t = threadIdx.x;
    const int kq = t >> 6;
    const int lane = t & 63;
    const int li = lane & 15;
    const int quad = lane >> 4;
    const int head = blockIdx.x & 7;
    const int stripe = blockIdx.x >> 3;
    const int i0 = stripe * 64;

    // phase 0: bitmask tile -> LDS (32 KB, coalesced)
    {
        const uint4* gsrc = (const uint4*)(abm + stripe * 8192);
        uint4* dst = (uint4*)bm;
        #pragma unroll
        for (int i = 0; i < 8; ++i) dst[t + 256 * i] = gsrc[t + 256 * i];
    }

    float a_[4], b_[4];
    #pragma unroll
    for (int g = 0; g < 4; ++g) {
        float sv = srcv[head * 4096 + i0 + 16 * g + li];
        a_[g] = sv;            // t1 = tt + sv
        b_[g] = 0.2f * sv;     // t2 = 0.2*tt + 0.2*sv
    }

    f32x4 acc[16];
    #pragma unroll
    for (int i = 0; i < 16; ++i) acc[i] = (f32x4){0.f, 0.f, 0.f, 0.f};
    float pd[4] = {0.f, 0.f, 0.f, 0.f};

    const float4* tgtp = (const float4*)(tgtv + head * 4096);
    const uint4*  ap   = (const uint4*)(htT2 + head * HT_STRIDE) + (li * 4 + quad);

    __syncthreads();

    const int c0 = kq * 32;
    // prefetch iter 0
    uint4 bw = ((const uint4*)bm)[c0 * 16 + li];
    float4 tg0 = tgtp[c0 * 8 + quad * 2 + 0];
    float4 tg1 = tgtp[c0 * 8 + quad * 2 + 1];
    uint4 av0 = ap[c0 * 256 + 0];
    uint4 av1 = ap[c0 * 256 + 64];
    uint4 av2 = ap[c0 * 256 + 128];
    uint4 av3 = ap[c0 * 256 + 192];

    #pragma unroll 1
    for (int ci = 0; ci < 32; ++ci) {
        const int cn = c0 + ((ci + 1) & 31);   // ci=31 harmlessly reloads
        uint4 nbw = ((const uint4*)bm)[cn * 16 + li];
        float4 ntg0 = tgtp[cn * 8 + quad * 2 + 0];
        float4 ntg1 = tgtp[cn * 8 + quad * 2 + 1];
        uint4 nav0 = ap[cn * 256 + 0];
        uint4 nav1 = ap[cn * 256 + 64];
        uint4 nav2 = ap[cn * 256 + 128];
        uint4 nav3 = ap[cn * 256 + 192];

        const float tt[8] = {tg0.x, tg0.y, tg0.z, tg0.w, tg1.x, tg1.y, tg1.z, tg1.w};
        const unsigned int wb[4] = {bw.x, bw.y, bw.z, bw.w};
        #pragma unroll
        for (int g = 0; g < 4; ++g) {
            const unsigned int wq = wb[g] >> (quad * 8);
            float wv[8];
            #pragma unroll
            for (int j = 0; j < 8; ++j) {
                float t1 = tt[j] + a_[g];
                float t2 = fmaf(tt[j], 0.2f, b_[g]);
                float e = fmaxf(t1, t2);               // lrelu(sv+tt)
                float p = __expf(e);                   // f32-safe, no max-sub
                wv[j] = (wq & (1u << j)) ? p : 0.f;
                pd[g] += wv[j];
            }
            unsigned int pk0, pk1, pk2, pk3;
            asm("v_cvt_pk_bf16_f32 %0, %1, %2" : "=v"(pk0) : "v"(wv[0]), "v"(wv[1]));
            asm("v_cvt_pk_bf16_f32 %0, %1, %2" : "=v"(pk1) : "v"(wv[2]), "v"(wv[3]));
            asm("v_cvt_pk_bf16_f32 %0, %1, %2" : "=v"(pk2) : "v"(wv[4]), "v"(wv[5]));
            asm("v_cvt_pk_bf16_f32 %0, %1, %2" : "=v"(pk3) : "v"(wv[6]), "v"(wv[7]));
            uint4 bv; bv.x = pk0; bv.y = pk1; bv.z = pk2; bv.w = pk3;
            bf16x8 bfrag = __builtin_bit_cast(bf16x8, bv);
            acc[g * 4 + 0] = __builtin_amdgcn_mfma_f32_16x16x32_bf16(__builtin_bit_cast(bf16x8, av0), bfrag, acc[g * 4 + 0], 0, 0, 0);
            acc[g * 4 + 1] = __builtin_amdgcn_mfma_f32_16x16x32_bf16(__builtin_bit_cast(bf16x8, av1), bfrag, acc[g * 4 + 1], 0, 0, 0);
            acc[g * 4 + 2] = __builtin_amdgcn_mfma_f32_16x16x32_bf16(__builtin_bit_cast(bf16x8, av2), bfrag, acc[g * 4 + 2], 0, 0, 0);
            acc[g * 4 + 3] = __builtin_amdgcn_mfma_f32_16x16x32_bf16(__builtin_bit_cast(bf16x8, av3), bfrag, acc[g * 4 + 3], 0, 0, 0);
        }
        bw = nbw; tg0 = ntg0; tg1 = ntg1;
        av0 = nav0; av1 = nav1; av2 = nav2; av3 = nav3;
    }

    // ---- phase 3: combine the 4 k-quarters, denominator, store ----
    __syncthreads();             // all waves done reading bm before overwrite
    float* comb = smem;          // union over bm region
    if (kq != 0) {
        float* cb = comb + ((kq - 1) * 64 + lane) * 68;   // 68 f32 = 272 B, 16B-aligned
        #pragma unroll
        for (int i = 0; i < 16; ++i) ((f32x4*)cb)[i] = acc[i];
        #pragma unroll
        for (int g = 0; g < 4; ++g) cb[64 + g] = pd[g];
    }
    __syncthreads();
    if (kq == 0) {
        #pragma unroll
        for (int q = 0; q < 3; ++q) {
            const float* cb = comb + (q * 64 + lane) * 68;
            #pragma unroll
            for (int i = 0; i < 16; ++i) acc[i] += ((const f32x4*)cb)[i];
            #pragma unroll
            for (int g = 0; g < 4; ++g) pd[g] += cb[64 + g];
        }
        #pragma unroll
        for (int g = 0; g < 4; ++g) {
            float p2 = pd[g];
            p2 += __shfl_xor(p2, 16, 64);
            p2 += __shfl_xor(p2, 32, 64);
            const float rd = 1.0f / p2;
            float4* op = (float4*)(out + head * HT_STRIDE + (i0 + 16 * g + li) * 64);
            #pragma unroll
            for (int f = 0; f < 4; ++f) {
                f32x4 a = acc[g * 4 + f];
                op[f * 4 + quad] = make_float4(a[0] * rd, a[1] * rd, a[2] * rd, a[3] * rd);
            }
        }
    }
}

extern "C" void kernel_launch(void* const* d_in, const int* in_sizes, int n_in,
                              void* d_out, int out_size, void* d_ws, size_t ws_size,
                              hipStream_t stream) {
    const float* h   = (const float*)d_in[0];  // (1,4096,128) f32
    const int*   adj = (const int*)d_in[1];    // (4096,4096) i32
    const float* W   = (const float*)d_in[2];  // (128,512) f32
    const float* aW  = (const float*)d_in[3];  // (8,128,1) f32
    float* out = (float*)d_out;                // (1,8,4096,64) f32

    // ws layout (6.25 MB): src | tgt | abm(2MB bitmask) | htT2(bf16 k-tiled)
    char* ws = (char*)d_ws;
    float* src  = (float*)(ws);
    float* tgt  = (float*)(ws + 131072);
    unsigned int*   abm  = (unsigned int*)(ws + 262144);
    unsigned short* htT2 = (unsigned short*)(ws + 2359296);
    float* ht = out;   // ht (f32) lives in d_out; k_attn overwrites it last

    hipLaunchKernelGGL(k_linear,  dim3(512), dim3(256), 0, stream, h, W, ht);
    hipLaunchKernelGGL(k_prep,    dim3(512), dim3(256), 0, stream, ht, aW, src, tgt, htT2);
    hipLaunchKernelGGL(k_adjmask, dim3(512), dim3(256), 0, stream, adj, abm);
    hipLaunchKernelGGL(k_attn,    dim3(512), dim3(256), 0, stream, abm, htT2, src, tgt, out);
}

// Round 3
// 156.827 us; speedup vs baseline: 1.4526x; 1.1293x over previous
//
#include <hip/hip_runtime.h>
#include <stdint.h>

#define HT_STRIDE 262144   // 4096*64 elements per head
#define LOG2E 1.4426950408889634f

typedef __attribute__((ext_vector_type(8))) short bf16x8;
typedef __attribute__((ext_vector_type(4))) float f32x4;

__device__ __forceinline__ unsigned short f2bf(float f) {
    unsigned int u = __float_as_uint(f);
    u += 0x7FFFu + ((u >> 16) & 1u);
    return (unsigned short)(u >> 16);
}

__device__ __forceinline__ float exp2_fast(float e) {
#if __has_builtin(__builtin_amdgcn_exp2f)
    return __builtin_amdgcn_exp2f(e);
#else
    return __expf(e * 0.6931471805599453f);   // expf(ln2*x) == 2^x
#endif
}

// ---------------------------------------------------------------------------
// Kernel 1 (heterogeneous fusion, 1024 blocks x 256 thr):
//  blocks 0..511   : adjacency (64 MB, read once at HBM rate) -> 2 MB bitmask
//                    abm[s64][c 128][li 16][g 4], bit k of word = adj row
//                    (s64*64+16g+li), col (32c+k).
//  blocks 512..1023: linear + prep. One block computes the 8x512 P-tile
//                    (P = h @ W) for P-rows 8*bid2.., which is exactly the
//                    64-node x 64-o ht tile of (head p0>>12, nodes p0&4095..).
//                    ht never touches global memory. Emits:
//                     - src/tgt projections, PRE-SCALED by log2(e)
//                     - bf16 k-tiled htT2[hd][m>>5][o][m&31]
//  The two halves are independent; HBM streaming (adjmask) overlaps with
//  L2/VALU work (linear) across the grid. 2 launches total for the net.
// ---------------------------------------------------------------------------
__global__ void __launch_bounds__(256) k_fused(const float* __restrict__ h,
                                               const int* __restrict__ adj,
                                               const float* __restrict__ W,
                                               const float* __restrict__ aW,
                                               float* __restrict__ src,
                                               float* __restrict__ tgt,
                                               unsigned short* __restrict__ htT2,
                                               unsigned int* __restrict__ abm) {
    __shared__ unsigned int ldsT[1024];
    __shared__ float hs[8][128];
    __shared__ float ldsA[64][66];
    __shared__ float redS[4][64];
    __shared__ float redT[4][64];
    const int t = threadIdx.x;

    if (blockIdx.x < 512) {
        // ---------------- adjmask half ----------------
        const int lane = t & 63;
        const int w = t >> 6;
        const int sb = blockIdx.x >> 3;
        const int cq = blockIdx.x & 7;
        for (int rr = 0; rr < 16; ++rr) {
            const int* arow = adj + (sb * 64 + w * 16 + rr) * 4096 + cq * 512;
            int v[8];
            #pragma unroll
            for (int j = 0; j < 8; ++j) v[j] = arow[j * 64 + lane];
            #pragma unroll
            for (int j = 0; j < 8; ++j) {
                unsigned long long m = __ballot(v[j] > 0);
                if (lane < 2)
                    ldsT[(2 * j + lane) * 64 + rr * 4 + w] = (unsigned int)(m >> (lane * 32));
            }
        }
        __syncthreads();
        ((uint4*)(abm + (sb * 128 + cq * 16) * 64))[t] = ((uint4*)ldsT)[t];
    } else {
        // ---------------- linear + prep half ----------------
        const int bid2 = (int)blockIdx.x - 512;
        const int n0 = bid2 * 8;            // P-row base (rows of h @ W)
        const int p0 = bid2 * 64;           // flat node base = hd*4096 + m0
        const int hd = p0 >> 12;
        const int m0 = p0 & 4095;

        // stage 8 h-rows (4 KB), coalesced
        {
            float4 v = ((const float4*)(h + n0 * 128))[t];
            int e = t * 4;
            int r = e >> 7, f = e & 127;
            hs[r][f + 0] = v.x; hs[r][f + 1] = v.y;
            hs[r][f + 2] = v.z; hs[r][f + 3] = v.w;
        }
        __syncthreads();

        // 8x512 P-tile: thread t owns cols (2t, 2t+1) for all 8 rows
        float acc0[8], acc1[8];
        #pragma unroll
        for (int r = 0; r < 8; ++r) { acc0[r] = 0.f; acc1[r] = 0.f; }
        const float2* Wf = (const float2*)W;
        for (int f = 0; f < 128; ++f) {
            float2 wp = Wf[f * 256 + t];
            #pragma unroll
            for (int r = 0; r < 8; ++r) {
                float hv = hs[r][f];
                acc0[r] = fmaf(hv, wp.x, acc0[r]);
                acc1[r] = fmaf(hv, wp.y, acc1[r]);
            }
        }
        // scatter into node-major tile: node = 8r + (2t)>>6, o = (2t)&63
        {
            const int ns = t >> 5;
            const int o = (2 * t) & 63;
            #pragma unroll
            for (int r = 0; r < 8; ++r) {
                *(float2*)&ldsA[r * 8 + ns][o] = make_float2(acc0[r], acc1[r]);
            }
        }
        __syncthreads();

        // src/tgt projections (pre-scaled by log2e for the exp2 path)
        {
            const int r = t & 63, og = t >> 6;
            float sdot = 0.f, gdot = 0.f;
            #pragma unroll
            for (int k = 0; k < 16; ++k) {
                int o = og * 16 + k;
                float hv = ldsA[r][o];
                sdot = fmaf(hv, aW[hd * 128 + o], sdot);
                gdot = fmaf(hv, aW[hd * 128 + 64 + o], gdot);
            }
            redS[og][r] = sdot; redT[og][r] = gdot;
        }
        __syncthreads();
        if (t < 64) {
            src[p0 + t] = (redS[0][t] + redS[1][t] + redS[2][t] + redS[3][t]) * LOG2E;
        } else if (t < 128) {
            int r = t - 64;
            tgt[p0 + r] = (redT[0][r] + redT[1][r] + redT[2][r] + redT[3][r]) * LOG2E;
        }

        // bf16 k-tiled transpose out (reads ldsA, stable since last barrier)
        unsigned short* d = htT2 + (hd * 128 + (m0 >> 5)) * 2048;
        #pragma unroll
        for (int i = 0; i < 16; ++i) {
            int id = t + 256 * i;
            int mi = id & 31, o = (id >> 5) & 63, ct = id >> 11;
            d[ct * 2048 + o * 32 + mi] = f2bf(ldsA[mi + 32 * ct][o]);
        }
    }
}

// ---------------------------------------------------------------------------
// Kernel 2 v5: fused GAT attention.
// grid 1024 x 256 thr: block = (head = bid&7  -> XCD-pinned L2 slice,
//                               s32  = bid>>3 -> 32-row stripe).
// 4 waves = 4 k-quarters; wave: 32 rows (2 g2-groups) x 32 c-iters.
// Per c-iter: 4 uint4 A-frags (reused by 2 row groups), 2 float4 tgt,
// 1 uint2 bitword (LDS), 16x{add,fma,max,exp2,cndmask,add}, 8 cvt_pk,
// 8 MFMA. No manual prefetch: 4 waves/SIMD (16 waves/CU) hide L2 latency.
// LDS union: bitmask (16 KB) then kq-combine (27.6 KB) -> 4 blocks/CU.
// src/tgt arrive pre-scaled by log2e -> raw v_exp, no per-element mul.
// ---------------------------------------------------------------------------
__global__ void __launch_bounds__(256, 4) k_attn(const unsigned int* __restrict__ abm,
                                                 const unsigned short* __restrict__ htT2,
                                                 const float* __restrict__ srcv,
                                                 const float* __restrict__ tgtv,
                                                 float* __restrict__ out) {
    __shared__ __align__(16) float smem[6912];   // 27648 B union
    uint2* bm2 = (uint2*)smem;

    const int t = threadIdx.x;
    const int kq = t >> 6;
    const int lane = t & 63;
    const int li = lane & 15;
    const int quad = lane >> 4;
    const int head = blockIdx.x & 7;
    const int s32 = blockIdx.x >> 3;         // 0..127
    const int s64 = s32 >> 1, half = s32 & 1;
    const int i0 = s32 * 32;

    // phase 0: this stripe's uint2 bitword slice -> LDS (16 KB, coalesced 8B)
    {
        const unsigned int* base = abm + s64 * 8192 + half * 2;
        #pragma unroll
        for (int i = 0; i < 8; ++i) {
            int p = t + 256 * i;             // p = c*16 + li
            int c = p >> 4, lw = p & 15;
            bm2[p] = *(const uint2*)(base + c * 64 + lw * 4);
        }
    }

    float a_[2], b_[2];
    #pragma unroll
    for (int g2 = 0; g2 < 2; ++g2) {
        float sv = srcv[head * 4096 + i0 + 16 * g2 + li];
        a_[g2] = sv;            // t1 = tt + sv            (both log2e-scaled)
        b_[g2] = 0.2f * sv;     // t2 = 0.2*tt + 0.2*sv
    }

    f32x4 acc[8];
    #pragma unroll
    for (int i = 0; i < 8; ++i) acc[i] = (f32x4){0.f, 0.f, 0.f, 0.f};
    float pd[2] = {0.f, 0.f};

    const float4* tgtp = (const float4*)(tgtv + head * 4096);
    const uint4*  ap   = (const uint4*)(htT2 + head * HT_STRIDE) + (li * 4 + quad);

    __syncthreads();

    const int c0 = kq * 32;
    #pragma unroll 1
    for (int ci = 0; ci < 32; ++ci) {
        const int c = c0 + ci;
        uint4 av0 = ap[c * 256 + 0];
        uint4 av1 = ap[c * 256 + 64];
        uint4 av2 = ap[c * 256 + 128];
        uint4 av3 = ap[c * 256 + 192];
        float4 tg0 = tgtp[c * 8 + quad * 2 + 0];
        float4 tg1 = tgtp[c * 8 + quad * 2 + 1];
        uint2 bw = bm2[c * 16 + li];

        const float tt[8] = {tg0.x, tg0.y, tg0.z, tg0.w, tg1.x, tg1.y, tg1.z, tg1.w};
        const unsigned int wb[2] = {bw.x, bw.y};
        #pragma unroll
        for (int g2 = 0; g2 < 2; ++g2) {
            const unsigned int wq = wb[g2] >> (quad * 8);
            float wv[8];
            #pragma unroll
            for (int j = 0; j < 8; ++j) {
                float t1 = tt[j] + a_[g2];
                float t2 = fmaf(tt[j], 0.2f, b_[g2]);
                float e = fmaxf(t1, t2);               // log2e * lrelu(sv+tt)
                float p = exp2_fast(e);
                wv[j] = (wq & (1u << j)) ? p : 0.f;
                pd[g2] += wv[j];
            }
            unsigned int pk0, pk1, pk2, pk3;
            asm("v_cvt_pk_bf16_f32 %0, %1, %2" : "=v"(pk0) : "v"(wv[0]), "v"(wv[1]));
            asm("v_cvt_pk_bf16_f32 %0, %1, %2" : "=v"(pk1) : "v"(wv[2]), "v"(wv[3]));
            asm("v_cvt_pk_bf16_f32 %0, %1, %2" : "=v"(pk2) : "v"(wv[4]), "v"(wv[5]));
            asm("v_cvt_pk_bf16_f32 %0, %1, %2" : "=v"(pk3) : "v"(wv[6]), "v"(wv[7]));
            uint4 bv; bv.x = pk0; bv.y = pk1; bv.z = pk2; bv.w = pk3;
            bf16x8 bfrag = __builtin_bit_cast(bf16x8, bv);
            acc[g2 * 4 + 0] = __builtin_amdgcn_mfma_f32_16x16x32_bf16(__builtin_bit_cast(bf16x8, av0), bfrag, acc[g2 * 4 + 0], 0, 0, 0);
            acc[g2 * 4 + 1] = __builtin_amdgcn_mfma_f32_16x16x32_bf16(__builtin_bit_cast(bf16x8, av1), bfrag, acc[g2 * 4 + 1], 0, 0, 0);
            acc[g2 * 4 + 2] = __builtin_amdgcn_mfma_f32_16x16x32_bf16(__builtin_bit_cast(bf16x8, av2), bfrag, acc[g2 * 4 + 2], 0, 0, 0);
            acc[g2 * 4 + 3] = __builtin_amdgcn_mfma_f32_16x16x32_bf16(__builtin_bit_cast(bf16x8, av3), bfrag, acc[g2 * 4 + 3], 0, 0, 0);
        }
    }

    // ---- phase 3: combine 4 k-quarters, denominator, store ----
    __syncthreads();             // all waves done with bm before overwrite
    if (kq != 0) {
        float* cb = smem + ((kq - 1) * 64 + lane) * 36;  // 144 B stride, 16B-aligned
        #pragma unroll
        for (int i = 0; i < 8; ++i) ((f32x4*)cb)[i] = acc[i];
        cb[32] = pd[0]; cb[33] = pd[1];
    }
    __syncthreads();
    if (kq == 0) {
        #pragma unroll
        for (int q = 0; q < 3; ++q) {
            const float* cb = smem + (q * 64 + lane) * 36;
            #pragma unroll
            for (int i = 0; i < 8; ++i) acc[i] += ((const f32x4*)cb)[i];
            pd[0] += cb[32]; pd[1] += cb[33];
        }
        #pragma unroll
        for (int g2 = 0; g2 < 2; ++g2) {
            float p2 = pd[g2];
            p2 += __shfl_xor(p2, 16, 64);
            p2 += __shfl_xor(p2, 32, 64);
            const float rd = 1.0f / p2;
            float4* op = (float4*)(out + head * HT_STRIDE + (i0 + 16 * g2 + li) * 64);
            #pragma unroll
            for (int f = 0; f < 4; ++f) {
                f32x4 a = acc[g2 * 4 + f];
                op[f * 4 + quad] = make_float4(a[0] * rd, a[1] * rd, a[2] * rd, a[3] * rd);
            }
        }
    }
}

extern "C" void kernel_launch(void* const* d_in, const int* in_sizes, int n_in,
                              void* d_out, int out_size, void* d_ws, size_t ws_size,
                              hipStream_t stream) {
    const float* h   = (const float*)d_in[0];  // (1,4096,128) f32
    const int*   adj = (const int*)d_in[1];    // (4096,4096) i32
    const float* W   = (const float*)d_in[2];  // (128,512) f32
    const float* aW  = (const float*)d_in[3];  // (8,128,1) f32
    float* out = (float*)d_out;                // (1,8,4096,64) f32

    // ws layout (6.25 MB, proven safe): src | tgt | abm(2MB) | htT2(4MB)
    char* ws = (char*)d_ws;
    float* src  = (float*)(ws);
    float* tgt  = (float*)(ws + 131072);
    unsigned int*   abm  = (unsigned int*)(ws + 262144);
    unsigned short* htT2 = (unsigned short*)(ws + 2359296);

    hipLaunchKernelGGL(k_fused, dim3(1024), dim3(256), 0, stream,
                       h, adj, W, aW, src, tgt, htT2, abm);
    hipLaunchKernelGGL(k_attn,  dim3(1024), dim3(256), 0, stream,
                       abm, htT2, src, tgt, out);
}

// Round 4
// 155.476 us; speedup vs baseline: 1.4652x; 1.0087x over previous
//
#include <hip/hip_runtime.h>
#include <stdint.h>

#define HT_STRIDE 262144   // 4096*64 elements per head
#define LOG2E 1.4426950408889634f

typedef __attribute__((ext_vector_type(8))) short bf16x8;
typedef __attribute__((ext_vector_type(4))) float f32x4;
typedef __attribute__((ext_vector_type(2))) float f32x2;

__device__ __forceinline__ unsigned short f2bf(float f) {
    unsigned int u = __float_as_uint(f);
    u += 0x7FFFu + ((u >> 16) & 1u);
    return (unsigned short)(u >> 16);
}

__device__ __forceinline__ float exp2_fast(float e) {
#if __has_builtin(__builtin_amdgcn_exp2f)
    return __builtin_amdgcn_exp2f(e);
#else
    return __expf(e * 0.6931471805599453f);   // expf(ln2*x) == 2^x
#endif
}

// ---------------------------------------------------------------------------
// Kernel 1 (heterogeneous fusion, 1024 blocks x 256 thr):
//  blocks 0..511   : adjacency (64 MB, read once at HBM rate) -> 2 MB bitmask
//                    abm[s64][c 128][li 16][g 4], bit k of word = adj row
//                    (s64*64+16g+li), col (32c+k).
//  blocks 512..1023: linear + prep (ht never touches global). Emits src/tgt
//                    (pre-scaled by log2e) + bf16 k-tiled htT2.
// ---------------------------------------------------------------------------
__global__ void __launch_bounds__(256) k_fused(const float* __restrict__ h,
                                               const int* __restrict__ adj,
                                               const float* __restrict__ W,
                                               const float* __restrict__ aW,
                                               float* __restrict__ src,
                                               float* __restrict__ tgt,
                                               unsigned short* __restrict__ htT2,
                                               unsigned int* __restrict__ abm) {
    __shared__ unsigned int ldsT[1024];
    __shared__ float hs[8][128];
    __shared__ float ldsA[64][66];
    __shared__ float redS[4][64];
    __shared__ float redT[4][64];
    const int t = threadIdx.x;

    if (blockIdx.x < 512) {
        // ---------------- adjmask half ----------------
        const int lane = t & 63;
        const int w = t >> 6;
        const int sb = blockIdx.x >> 3;
        const int cq = blockIdx.x & 7;
        for (int rr = 0; rr < 16; ++rr) {
            const int* arow = adj + (sb * 64 + w * 16 + rr) * 4096 + cq * 512;
            int v[8];
            #pragma unroll
            for (int j = 0; j < 8; ++j) v[j] = arow[j * 64 + lane];
            #pragma unroll
            for (int j = 0; j < 8; ++j) {
                unsigned long long m = __ballot(v[j] > 0);
                if (lane < 2)
                    ldsT[(2 * j + lane) * 64 + rr * 4 + w] = (unsigned int)(m >> (lane * 32));
            }
        }
        __syncthreads();
        ((uint4*)(abm + (sb * 128 + cq * 16) * 64))[t] = ((uint4*)ldsT)[t];
    } else {
        // ---------------- linear + prep half ----------------
        const int bid2 = (int)blockIdx.x - 512;
        const int n0 = bid2 * 8;            // P-row base (rows of h @ W)
        const int p0 = bid2 * 64;           // flat node base = hd*4096 + m0
        const int hd = p0 >> 12;
        const int m0 = p0 & 4095;

        // stage 8 h-rows (4 KB), coalesced
        {
            float4 v = ((const float4*)(h + n0 * 128))[t];
            int e = t * 4;
            int r = e >> 7, f = e & 127;
            hs[r][f + 0] = v.x; hs[r][f + 1] = v.y;
            hs[r][f + 2] = v.z; hs[r][f + 3] = v.w;
        }
        __syncthreads();

        // 8x512 P-tile: thread t owns cols (2t, 2t+1) for all 8 rows
        float acc0[8], acc1[8];
        #pragma unroll
        for (int r = 0; r < 8; ++r) { acc0[r] = 0.f; acc1[r] = 0.f; }
        const float2* Wf = (const float2*)W;
        for (int f = 0; f < 128; ++f) {
            float2 wp = Wf[f * 256 + t];
            #pragma unroll
            for (int r = 0; r < 8; ++r) {
                float hv = hs[r][f];
                acc0[r] = fmaf(hv, wp.x, acc0[r]);
                acc1[r] = fmaf(hv, wp.y, acc1[r]);
            }
        }
        // scatter into node-major tile: node = 8r + (2t)>>6, o = (2t)&63
        {
            const int ns = t >> 5;
            const int o = (2 * t) & 63;
            #pragma unroll
            for (int r = 0; r < 8; ++r) {
                *(float2*)&ldsA[r * 8 + ns][o] = make_float2(acc0[r], acc1[r]);
            }
        }
        __syncthreads();

        // src/tgt projections (pre-scaled by log2e for the exp2 path)
        {
            const int r = t & 63, og = t >> 6;
            float sdot = 0.f, gdot = 0.f;
            #pragma unroll
            for (int k = 0; k < 16; ++k) {
                int o = og * 16 + k;
                float hv = ldsA[r][o];
                sdot = fmaf(hv, aW[hd * 128 + o], sdot);
                gdot = fmaf(hv, aW[hd * 128 + 64 + o], gdot);
            }
            redS[og][r] = sdot; redT[og][r] = gdot;
        }
        __syncthreads();
        if (t < 64) {
            src[p0 + t] = (redS[0][t] + redS[1][t] + redS[2][t] + redS[3][t]) * LOG2E;
        } else if (t < 128) {
            int r = t - 64;
            tgt[p0 + r] = (redT[0][r] + redT[1][r] + redT[2][r] + redT[3][r]) * LOG2E;
        }

        // bf16 k-tiled transpose out (reads ldsA, stable since last barrier)
        unsigned short* d = htT2 + (hd * 128 + (m0 >> 5)) * 2048;
        #pragma unroll
        for (int i = 0; i < 16; ++i) {
            int id = t + 256 * i;
            int mi = id & 31, o = (id >> 5) & 63, ct = id >> 11;
            d[ct * 2048 + o * 32 + mi] = f2bf(ldsA[mi + 32 * ct][o]);
        }
    }
}

// ---------------------------------------------------------------------------
// Kernel 2 v6: fused GAT attention.
// grid 1024 x 256: block = (head = bid&7 -> XCD-pinned, s32 = bid>>3).
// 4 waves = 4 k-quarters; wave: 32 rows (2 g2) x 32 c-iters.
// v6 changes vs v5 (VALU diet + latency):
//  - tgt staged in LDS (16 KB): per-iter tgt reads are broadcast ds_read_b128
//  - pd via ones-A MFMA (denominator on the idle MFMA pipe; kills 16 adds
//    + the final shfl pair; numerator/denominator use the SAME bf16 weights)
//  - A-frag loads explicitly double-buffered, unroll 2 (static buf index)
//  - t1/t2 in packed f32 (v_pk_add/v_pk_fma)
// LDS union: [tgt 16KB | bm 16KB] -> comb 27.6KB. 4 blocks/CU = 128KB.
// ---------------------------------------------------------------------------
__global__ void __launch_bounds__(256, 4) k_attn(const unsigned int* __restrict__ abm,
                                                 const unsigned short* __restrict__ htT2,
                                                 const float* __restrict__ srcv,
                                                 const float* __restrict__ tgtv,
                                                 float* __restrict__ out) {
    __shared__ __align__(16) float smem[8192];    // 32 KB union
    float* tgl = smem;                            // [4096] f32
    uint2* bm2 = (uint2*)(smem + 4096);           // [2048] uint2

    const int t = threadIdx.x;
    const int kq = t >> 6;
    const int lane = t & 63;
    const int li = lane & 15;
    const int quad = lane >> 4;
    const int head = blockIdx.x & 7;
    const int s32 = blockIdx.x >> 3;         // 0..127
    const int s64 = s32 >> 1, half = s32 & 1;
    const int i0 = s32 * 32;

    // phase 0: stage tgt slice (16 KB) + bitmask slice (16 KB) into LDS
    {
        const float4* tsrc = (const float4*)(tgtv + head * 4096);
        float4* tdst = (float4*)tgl;
        #pragma unroll
        for (int i = 0; i < 4; ++i) tdst[t + 256 * i] = tsrc[t + 256 * i];

        const unsigned int* base = abm + s64 * 8192 + half * 2;
        #pragma unroll
        for (int i = 0; i < 8; ++i) {
            int p = t + 256 * i;             // p = c*16 + li
            int c = p >> 4, lw = p & 15;
            bm2[p] = *(const uint2*)(base + c * 64 + lw * 4);
        }
    }

    f32x2 a2[2], b2[2];
    #pragma unroll
    for (int g2 = 0; g2 < 2; ++g2) {
        float sv = srcv[head * 4096 + i0 + 16 * g2 + li];
        a2[g2] = (f32x2){sv, sv};                       // t1 = tt + sv
        b2[g2] = (f32x2){0.2f * sv, 0.2f * sv};         // t2 = 0.2*tt + 0.2*sv
    }

    f32x4 acc[8];
    #pragma unroll
    for (int i = 0; i < 8; ++i) acc[i] = (f32x4){0.f, 0.f, 0.f, 0.f};
    f32x4 apd[2];
    apd[0] = (f32x4){0.f, 0.f, 0.f, 0.f};
    apd[1] = (f32x4){0.f, 0.f, 0.f, 0.f};

    const uint4 onesw = {0x3F803F80u, 0x3F803F80u, 0x3F803F80u, 0x3F803F80u};
    const bf16x8 aones = __builtin_bit_cast(bf16x8, onesw);

    const uint4* ap = (const uint4*)(htT2 + head * HT_STRIDE) + (li * 4 + quad);

    __syncthreads();

    const int c0 = kq * 32;
    uint4 avb[2][4];
    #pragma unroll
    for (int f = 0; f < 4; ++f) avb[0][f] = ap[c0 * 256 + f * 64];

    #pragma unroll 2
    for (int ci = 0; ci < 32; ++ci) {
        const int cur = ci & 1;
        const int c = c0 + ci;
        const int cn = c0 + ((ci + 1) & 31);   // ci=31 harmlessly reloads
        #pragma unroll
        for (int f = 0; f < 4; ++f) avb[cur ^ 1][f] = ap[cn * 256 + f * 64];

        const float* tk = tgl + c * 32 + quad * 8;
        float4 tg0 = ((const float4*)tk)[0];
        float4 tg1 = ((const float4*)tk)[1];
        uint2 bw = bm2[c * 16 + li];

        const float tt[8] = {tg0.x, tg0.y, tg0.z, tg0.w, tg1.x, tg1.y, tg1.z, tg1.w};
        const unsigned int wb[2] = {bw.x, bw.y};
        #pragma unroll
        for (int g2 = 0; g2 < 2; ++g2) {
            const unsigned int wq = wb[g2] >> (quad * 8);
            unsigned int pk[4];
            #pragma unroll
            for (int m = 0; m < 4; ++m) {
                f32x2 tp = (f32x2){tt[2 * m], tt[2 * m + 1]};
                f32x2 t1 = tp + a2[g2];                       // v_pk_add_f32
                f32x2 t2 = tp * 0.2f + b2[g2];                // v_pk_fma_f32
                float p0e = exp2_fast(fmaxf(t1[0], t2[0]));
                float p1e = exp2_fast(fmaxf(t1[1], t2[1]));
                float w0 = (wq & (1u << (2 * m)))     ? p0e : 0.f;
                float w1 = (wq & (1u << (2 * m + 1))) ? p1e : 0.f;
                asm("v_cvt_pk_bf16_f32 %0, %1, %2" : "=v"(pk[m]) : "v"(w0), "v"(w1));
            }
            uint4 bv; bv.x = pk[0]; bv.y = pk[1]; bv.z = pk[2]; bv.w = pk[3];
            bf16x8 bfrag = __builtin_bit_cast(bf16x8, bv);
            apd[g2] = __builtin_amdgcn_mfma_f32_16x16x32_bf16(aones, bfrag, apd[g2], 0, 0, 0);
            acc[g2 * 4 + 0] = __builtin_amdgcn_mfma_f32_16x16x32_bf16(__builtin_bit_cast(bf16x8, avb[cur][0]), bfrag, acc[g2 * 4 + 0], 0, 0, 0);
            acc[g2 * 4 + 1] = __builtin_amdgcn_mfma_f32_16x16x32_bf16(__builtin_bit_cast(bf16x8, avb[cur][1]), bfrag, acc[g2 * 4 + 1], 0, 0, 0);
            acc[g2 * 4 + 2] = __builtin_amdgcn_mfma_f32_16x16x32_bf16(__builtin_bit_cast(bf16x8, avb[cur][2]), bfrag, acc[g2 * 4 + 2], 0, 0, 0);
            acc[g2 * 4 + 3] = __builtin_amdgcn_mfma_f32_16x16x32_bf16(__builtin_bit_cast(bf16x8, avb[cur][3]), bfrag, acc[g2 * 4 + 3], 0, 0, 0);
        }
    }

    // ---- phase 3: combine 4 k-quarters, denominator, store ----
    __syncthreads();             // all waves done with tgl/bm before overwrite
    if (kq != 0) {
        float* cb = smem + ((kq - 1) * 64 + lane) * 36;  // 144 B stride, 16B-aligned
        #pragma unroll
        for (int i = 0; i < 8; ++i) ((f32x4*)cb)[i] = acc[i];
        cb[32] = apd[0][0]; cb[33] = apd[1][0];
    }
    __syncthreads();
    if (kq == 0) {
        float pd[2] = {apd[0][0], apd[1][0]};
        #pragma unroll
        for (int q = 0; q < 3; ++q) {
            const float* cb = smem + (q * 64 + lane) * 36;
            #pragma unroll
            for (int i = 0; i < 8; ++i) acc[i] += ((const f32x4*)cb)[i];
            pd[0] += cb[32]; pd[1] += cb[33];
        }
        #pragma unroll
        for (int g2 = 0; g2 < 2; ++g2) {
            const float rd = 1.0f / pd[g2];   // MFMA-ones already summed quads
            float4* op = (float4*)(out + head * HT_STRIDE + (i0 + 16 * g2 + li) * 64);
            #pragma unroll
            for (int f = 0; f < 4; ++f) {
                f32x4 a = acc[g2 * 4 + f];
                op[f * 4 + quad] = make_float4(a[0] * rd, a[1] * rd, a[2] * rd, a[3] * rd);
            }
        }
    }
}

extern "C" void kernel_launch(void* const* d_in, const int* in_sizes, int n_in,
                              void* d_out, int out_size, void* d_ws, size_t ws_size,
                              hipStream_t stream) {
    const float* h   = (const float*)d_in[0];  // (1,4096,128) f32
    const int*   adj = (const int*)d_in[1];    // (4096,4096) i32
    const float* W   = (const float*)d_in[2];  // (128,512) f32
    const float* aW  = (const float*)d_in[3];  // (8,128,1) f32
    float* out = (float*)d_out;                // (1,8,4096,64) f32

    // ws layout (6.25 MB, proven safe): src | tgt | abm(2MB) | htT2(4MB)
    char* ws = (char*)d_ws;
    float* src  = (float*)(ws);
    float* tgt  = (float*)(ws + 131072);
    unsigned int*   abm  = (unsigned int*)(ws + 262144);
    unsigned short* htT2 = (unsigned short*)(ws + 2359296);

    hipLaunchKernelGGL(k_fused, dim3(1024), dim3(256), 0, stream,
                       h, adj, W, aW, src, tgt, htT2, abm);
    hipLaunchKernelGGL(k_attn,  dim3(1024), dim3(256), 0, stream,
                       abm, htT2, src, tgt, out);
}

// Round 5
// 150.841 us; speedup vs baseline: 1.5102x; 1.0307x over previous
//
#include <hip/hip_runtime.h>
#include <stdint.h>

#define HT_STRIDE 262144   // 4096*64 elements per head
#define LOG2E 1.4426950408889634f

typedef __attribute__((ext_vector_type(8))) short bf16x8;
typedef __attribute__((ext_vector_type(4))) float f32x4;
typedef __attribute__((ext_vector_type(2))) float f32x2;

__device__ __forceinline__ unsigned short f2bf(float f) {
    unsigned int u = __float_as_uint(f);
    u += 0x7FFFu + ((u >> 16) & 1u);
    return (unsigned short)(u >> 16);
}

__device__ __forceinline__ float exp2_fast(float e) {
#if __has_builtin(__builtin_amdgcn_exp2f)
    return __builtin_amdgcn_exp2f(e);
#else
    return __expf(e * 0.6931471805599453f);   // expf(ln2*x) == 2^x
#endif
}

// ---------------------------------------------------------------------------
// Kernel 1 (heterogeneous fusion, 1024 blocks x 256 thr):
//  blocks 0..511   : adjacency (64 MB, read once at HBM rate) -> 2 MB bitmask
//                    abm[s64][c 128][li 16][g 4], bit k of word = adj row
//                    (s64*64+16g+li), col (32c+k).
//  blocks 512..1023: linear + prep (ht never touches global). Emits:
//                     - srcv: s' = src_dot * log2e  (per row)
//                     - ets:  (2^{t'}, 2^{0.2 t'}) pairs per col
//                       (piecewise-rank-1 factorization of exp(lrelu(s+t)):
//                        pos branch es*et, neg branch es2*et2; branch test
//                        et > 2^{-s'} -- exp is monotone)
//                     - bf16 k-tiled htT2
// ---------------------------------------------------------------------------
__global__ void __launch_bounds__(256) k_fused(const float* __restrict__ h,
                                               const int* __restrict__ adj,
                                               const float* __restrict__ W,
                                               const float* __restrict__ aW,
                                               float* __restrict__ srcv,
                                               float* __restrict__ ets,
                                               unsigned short* __restrict__ htT2,
                                               unsigned int* __restrict__ abm) {
    __shared__ unsigned int ldsT[1024];
    __shared__ float hs[8][128];
    __shared__ float ldsA[64][66];
    __shared__ float redS[4][64];
    __shared__ float redT[4][64];
    const int t = threadIdx.x;

    if (blockIdx.x < 512) {
        // ---------------- adjmask half ----------------
        const int lane = t & 63;
        const int w = t >> 6;
        const int sb = blockIdx.x >> 3;
        const int cq = blockIdx.x & 7;
        for (int rr = 0; rr < 16; ++rr) {
            const int* arow = adj + (sb * 64 + w * 16 + rr) * 4096 + cq * 512;
            int v[8];
            #pragma unroll
            for (int j = 0; j < 8; ++j) v[j] = arow[j * 64 + lane];
            #pragma unroll
            for (int j = 0; j < 8; ++j) {
                unsigned long long m = __ballot(v[j] > 0);
                if (lane < 2)
                    ldsT[(2 * j + lane) * 64 + rr * 4 + w] = (unsigned int)(m >> (lane * 32));
            }
        }
        __syncthreads();
        ((uint4*)(abm + (sb * 128 + cq * 16) * 64))[t] = ((uint4*)ldsT)[t];
    } else {
        // ---------------- linear + prep half ----------------
        const int bid2 = (int)blockIdx.x - 512;
        const int n0 = bid2 * 8;            // P-row base (rows of h @ W)
        const int p0 = bid2 * 64;           // flat node base = hd*4096 + m0
        const int hd = p0 >> 12;
        const int m0 = p0 & 4095;

        // stage 8 h-rows (4 KB), coalesced
        {
            float4 v = ((const float4*)(h + n0 * 128))[t];
            int e = t * 4;
            int r = e >> 7, f = e & 127;
            hs[r][f + 0] = v.x; hs[r][f + 1] = v.y;
            hs[r][f + 2] = v.z; hs[r][f + 3] = v.w;
        }
        __syncthreads();

        // 8x512 P-tile: thread t owns cols (2t, 2t+1) for all 8 rows
        float acc0[8], acc1[8];
        #pragma unroll
        for (int r = 0; r < 8; ++r) { acc0[r] = 0.f; acc1[r] = 0.f; }
        const float2* Wf = (const float2*)W;
        for (int f = 0; f < 128; ++f) {
            float2 wp = Wf[f * 256 + t];
            #pragma unroll
            for (int r = 0; r < 8; ++r) {
                float hv = hs[r][f];
                acc0[r] = fmaf(hv, wp.x, acc0[r]);
                acc1[r] = fmaf(hv, wp.y, acc1[r]);
            }
        }
        // scatter into node-major tile: node = 8r + (2t)>>6, o = (2t)&63
        {
            const int ns = t >> 5;
            const int o = (2 * t) & 63;
            #pragma unroll
            for (int r = 0; r < 8; ++r) {
                *(float2*)&ldsA[r * 8 + ns][o] = make_float2(acc0[r], acc1[r]);
            }
        }
        __syncthreads();

        // src/tgt projections
        {
            const int r = t & 63, og = t >> 6;
            float sdot = 0.f, gdot = 0.f;
            #pragma unroll
            for (int k = 0; k < 16; ++k) {
                int o = og * 16 + k;
                float hv = ldsA[r][o];
                sdot = fmaf(hv, aW[hd * 128 + o], sdot);
                gdot = fmaf(hv, aW[hd * 128 + 64 + o], gdot);
            }
            redS[og][r] = sdot; redT[og][r] = gdot;
        }
        __syncthreads();
        if (t < 64) {
            srcv[p0 + t] = (redS[0][t] + redS[1][t] + redS[2][t] + redS[3][t]) * LOG2E;
        } else if (t < 128) {
            int r = t - 64;
            float tv = (redT[0][r] + redT[1][r] + redT[2][r] + redT[3][r]) * LOG2E;
            ets[(p0 + r) * 2 + 0] = exp2_fast(tv);
            ets[(p0 + r) * 2 + 1] = exp2_fast(0.2f * tv);
        }

        // bf16 k-tiled transpose out (reads ldsA, stable since last barrier)
        unsigned short* d = htT2 + (hd * 128 + (m0 >> 5)) * 2048;
        #pragma unroll
        for (int i = 0; i < 16; ++i) {
            int id = t + 256 * i;
            int mi = id & 31, o = (id >> 5) & 63, ct = id >> 11;
            d[ct * 2048 + o * 32 + mi] = f2bf(ldsA[mi + 32 * ct][o]);
        }
    }
}

// ---------------------------------------------------------------------------
// Kernel 2 v7: fused GAT attention, transcendental-free inner loop.
// grid 1024 x 256: block = (head = bid&7 -> XCD-pinned, s32 = bid>>3).
// 4 waves = 4 k-quarters; wave: 32 rows (2 g2) x 32 c-iters.
// Piecewise-rank-1 weights: w(r,c) = mask * (et_c > eth_r ? es_r*et_c
//                                                         : es2_r*et2_c)
// Per elem: cmp + cndmask(et) + cndmask(es) + 1/2 pk_mul + 1/2 cvt_pk
//           + amortized halfword mask-AND. No exp, no trans-pipe chain.
// Bitmask words read directly from global (L2-resident) each c-iter.
// LDS: 32 KB ets table (quad-broadcast, 2-way bank alias = free);
// comb (27.6 KB) unions in afterward. 4 blocks/CU. pd via ones-A MFMA.
// ---------------------------------------------------------------------------
__global__ void __launch_bounds__(256, 4) k_attn(const unsigned int* __restrict__ abm,
                                                 const unsigned short* __restrict__ htT2,
                                                 const float* __restrict__ srcv,
                                                 const float* __restrict__ ets,
                                                 float* __restrict__ out) {
    __shared__ __align__(16) float smem[8192];    // 32 KB: ets slice -> comb union

    const int t = threadIdx.x;
    const int kq = t >> 6;
    const int lane = t & 63;
    const int li = lane & 15;
    const int quad = lane >> 4;
    const int head = blockIdx.x & 7;
    const int s32 = blockIdx.x >> 3;         // 0..127
    const int s64 = s32 >> 1, half = s32 & 1;
    const int i0 = s32 * 32;

    // phase 0: stage ets head-slice (4096 cols x (et,et2) = 32 KB)
    {
        const float4* esrc = (const float4*)(ets + head * 8192);
        float4* edst = (float4*)smem;
        #pragma unroll
        for (int i = 0; i < 8; ++i) edst[t + 256 * i] = esrc[t + 256 * i];
    }

    // per-row constants (3 exp2 per g2, once per kernel)
    float es[2], es2[2], eth[2];
    #pragma unroll
    for (int g2 = 0; g2 < 2; ++g2) {
        float sp = srcv[head * 4096 + i0 + 16 * g2 + li];   // s * log2e
        es[g2]  = exp2_fast(sp);
        es2[g2] = exp2_fast(0.2f * sp);
        eth[g2] = exp2_fast(-sp);
    }

    f32x4 acc[8];
    #pragma unroll
    for (int i = 0; i < 8; ++i) acc[i] = (f32x4){0.f, 0.f, 0.f, 0.f};
    f32x4 apd[2];
    apd[0] = (f32x4){0.f, 0.f, 0.f, 0.f};
    apd[1] = (f32x4){0.f, 0.f, 0.f, 0.f};

    const uint4 onesw = {0x3F803F80u, 0x3F803F80u, 0x3F803F80u, 0x3F803F80u};
    const bf16x8 aones = __builtin_bit_cast(bf16x8, onesw);

    const uint4* ap = (const uint4*)(htT2 + head * HT_STRIDE) + (li * 4 + quad);
    const unsigned int* bmp = abm + s64 * 8192 + half * 2 + li * 4;

    __syncthreads();

    const int c0 = kq * 32;
    #pragma unroll 1
    for (int ci = 0; ci < 32; ++ci) {
        const int c = c0 + ci;
        uint4 av0 = ap[c * 256 + 0];
        uint4 av1 = ap[c * 256 + 64];
        uint4 av2 = ap[c * 256 + 128];
        uint4 av3 = ap[c * 256 + 192];
        uint2 bw = *(const uint2*)(bmp + c * 64);     // L2-resident bitwords

        // (et, et2) pairs for this quad's 8 cols (LDS broadcast reads)
        const float4* ep = (const float4*)(smem + c * 64 + quad * 16);
        float4 e0 = ep[0], e1 = ep[1], e2 = ep[2], e3 = ep[3];
        const float etv[8]  = {e0.x, e0.z, e1.x, e1.z, e2.x, e2.z, e3.x, e3.z};
        const float et2v[8] = {e0.y, e0.w, e1.y, e1.w, e2.y, e2.w, e3.y, e3.w};

        const unsigned int wb[2] = {bw.x, bw.y};
        #pragma unroll
        for (int g2 = 0; g2 < 2; ++g2) {
            const unsigned int wq = wb[g2] >> (quad * 8);
            unsigned int pk[4];
            #pragma unroll
            for (int m = 0; m < 4; ++m) {
                const int j0 = 2 * m, j1 = 2 * m + 1;
                const bool cb0 = etv[j0] > eth[g2];
                const bool cb1 = etv[j1] > eth[g2];
                f32x2 ee, ss;
                ee[0] = cb0 ? etv[j0] : et2v[j0];
                ee[1] = cb1 ? etv[j1] : et2v[j1];
                ss[0] = cb0 ? es[g2] : es2[g2];
                ss[1] = cb1 ? es[g2] : es2[g2];
                f32x2 ww = ee * ss;                    // v_pk_mul_f32
                unsigned int pkm;
                asm("v_cvt_pk_bf16_f32 %0, %1, %2" : "=v"(pkm) : "v"(ww[0]), "v"(ww[1]));
                // halfword mask from adjacency bits j0,j1 (sext -> bfi -> and)
                const unsigned int lo = (unsigned int)((int)(wq << (31 - j0)) >> 31);
                const unsigned int hi = (unsigned int)((int)(wq << (31 - j1)) >> 31);
                const unsigned int msk = (lo & 0x0000FFFFu) | (hi & 0xFFFF0000u);
                pk[m] = pkm & msk;
            }
            uint4 bv; bv.x = pk[0]; bv.y = pk[1]; bv.z = pk[2]; bv.w = pk[3];
            bf16x8 bfrag = __builtin_bit_cast(bf16x8, bv);
            apd[g2] = __builtin_amdgcn_mfma_f32_16x16x32_bf16(aones, bfrag, apd[g2], 0, 0, 0);
            acc[g2 * 4 + 0] = __builtin_amdgcn_mfma_f32_16x16x32_bf16(__builtin_bit_cast(bf16x8, av0), bfrag, acc[g2 * 4 + 0], 0, 0, 0);
            acc[g2 * 4 + 1] = __builtin_amdgcn_mfma_f32_16x16x32_bf16(__builtin_bit_cast(bf16x8, av1), bfrag, acc[g2 * 4 + 1], 0, 0, 0);
            acc[g2 * 4 + 2] = __builtin_amdgcn_mfma_f32_16x16x32_bf16(__builtin_bit_cast(bf16x8, av2), bfrag, acc[g2 * 4 + 2], 0, 0, 0);
            acc[g2 * 4 + 3] = __builtin_amdgcn_mfma_f32_16x16x32_bf16(__builtin_bit_cast(bf16x8, av3), bfrag, acc[g2 * 4 + 3], 0, 0, 0);
        }
    }

    // ---- phase 3: combine 4 k-quarters, denominator, store ----
    __syncthreads();             // all waves done with ets table before overwrite
    if (kq != 0) {
        float* cb = smem + ((kq - 1) * 64 + lane) * 36;  // 144 B stride, 16B-aligned
        #pragma unroll
        for (int i = 0; i < 8; ++i) ((f32x4*)cb)[i] = acc[i];
        cb[32] = apd[0][0]; cb[33] = apd[1][0];
    }
    __syncthreads();
    if (kq == 0) {
        float pd[2] = {apd[0][0], apd[1][0]};
        #pragma unroll
        for (int q = 0; q < 3; ++q) {
            const float* cb = smem + (q * 64 + lane) * 36;
            #pragma unroll
            for (int i = 0; i < 8; ++i) acc[i] += ((const f32x4*)cb)[i];
            pd[0] += cb[32]; pd[1] += cb[33];
        }
        #pragma unroll
        for (int g2 = 0; g2 < 2; ++g2) {
            const float rd = 1.0f / pd[g2];   // ones-MFMA already summed quads
            float4* op = (float4*)(out + head * HT_STRIDE + (i0 + 16 * g2 + li) * 64);
            #pragma unroll
            for (int f = 0; f < 4; ++f) {
                f32x4 a = acc[g2 * 4 + f];
                op[f * 4 + quad] = make_float4(a[0] * rd, a[1] * rd, a[2] * rd, a[3] * rd);
            }
        }
    }
}

extern "C" void kernel_launch(void* const* d_in, const int* in_sizes, int n_in,
                              void* d_out, int out_size, void* d_ws, size_t ws_size,
                              hipStream_t stream) {
    const float* h   = (const float*)d_in[0];  // (1,4096,128) f32
    const int*   adj = (const int*)d_in[1];    // (4096,4096) i32
    const float* W   = (const float*)d_in[2];  // (128,512) f32
    const float* aW  = (const float*)d_in[3];  // (8,128,1) f32
    float* out = (float*)d_out;                // (1,8,4096,64) f32

    // ws layout (6.375 MB): srcv(128K) | ets(256K) | abm(2MB) | htT2(4MB)
    char* ws = (char*)d_ws;
    float* srcv = (float*)(ws);
    float* ets  = (float*)(ws + 131072);
    unsigned int*   abm  = (unsigned int*)(ws + 393216);
    unsigned short* htT2 = (unsigned short*)(ws + 2490368);

    hipLaunchKernelGGL(k_fused, dim3(1024), dim3(256), 0, stream,
                       h, adj, W, aW, srcv, ets, htT2, abm);
    hipLaunchKernelGGL(k_attn,  dim3(1024), dim3(256), 0, stream,
                       abm, htT2, srcv, ets, out);
}

// Round 6
// 149.655 us; speedup vs baseline: 1.5222x; 1.0079x over previous
//
#include <hip/hip_runtime.h>
#include <stdint.h>

#define HT_STRIDE 262144   // 4096*64 elements per head
#define LOG2E 1.4426950408889634f

typedef __attribute__((ext_vector_type(8))) short bf16x8;
typedef __attribute__((ext_vector_type(4))) float f32x4;
typedef __attribute__((ext_vector_type(2))) float f32x2;

__device__ __forceinline__ unsigned short f2bf(float f) {
    unsigned int u = __float_as_uint(f);
    u += 0x7FFFu + ((u >> 16) & 1u);
    return (unsigned short)(u >> 16);
}

__device__ __forceinline__ float exp2_fast(float e) {
#if __has_builtin(__builtin_amdgcn_exp2f)
    return __builtin_amdgcn_exp2f(e);
#else
    return __expf(e * 0.6931471805599453f);   // expf(ln2*x) == 2^x
#endif
}

// ---------------------------------------------------------------------------
// Kernel 1 (heterogeneous fusion, 1024 blocks x 256 thr):
//  blocks 0..511   : adjacency (64 MB, read once at HBM rate) -> 2 MB bitmask
//                    abm[s64][c 128][li 16][g 4], bit k of word = adj row
//                    (s64*64+16g+li), col (32c+k).
//  blocks 512..1023: linear + prep (ht never touches global). Emits:
//                     - ess: [head][{es,es2}][4096]  es=e^{s}, es2=e^{0.2s}
//                     - ets: [head][{et,et2}][4096]  (SoA -> pk_mul-friendly)
//                       max-of-products identity: exp(lrelu(s+t)) =
//                       max(es*et, es2*et2)  (exp and max commute)
//                     - bf16 k-tiled htT2
// ---------------------------------------------------------------------------
__global__ void __launch_bounds__(256) k_fused(const float* __restrict__ h,
                                               const int* __restrict__ adj,
                                               const float* __restrict__ W,
                                               const float* __restrict__ aW,
                                               float* __restrict__ ess,
                                               float* __restrict__ ets,
                                               unsigned short* __restrict__ htT2,
                                               unsigned int* __restrict__ abm) {
    __shared__ unsigned int ldsT[1024];
    __shared__ float hs[8][128];
    __shared__ float ldsA[64][66];
    __shared__ float redS[4][64];
    __shared__ float redT[4][64];
    const int t = threadIdx.x;

    if (blockIdx.x < 512) {
        // ---------------- adjmask half ----------------
        const int lane = t & 63;
        const int w = t >> 6;
        const int sb = blockIdx.x >> 3;
        const int cq = blockIdx.x & 7;
        for (int rr = 0; rr < 16; ++rr) {
            const int* arow = adj + (sb * 64 + w * 16 + rr) * 4096 + cq * 512;
            int v[8];
            #pragma unroll
            for (int j = 0; j < 8; ++j) v[j] = arow[j * 64 + lane];
            #pragma unroll
            for (int j = 0; j < 8; ++j) {
                unsigned long long m = __ballot(v[j] > 0);
                if (lane < 2)
                    ldsT[(2 * j + lane) * 64 + rr * 4 + w] = (unsigned int)(m >> (lane * 32));
            }
        }
        __syncthreads();
        ((uint4*)(abm + (sb * 128 + cq * 16) * 64))[t] = ((uint4*)ldsT)[t];
    } else {
        // ---------------- linear + prep half ----------------
        const int bid2 = (int)blockIdx.x - 512;
        const int n0 = bid2 * 8;            // P-row base (rows of h @ W)
        const int p0 = bid2 * 64;           // flat node base = hd*4096 + m0
        const int hd = p0 >> 12;
        const int m0 = p0 & 4095;

        // stage 8 h-rows (4 KB), coalesced
        {
            float4 v = ((const float4*)(h + n0 * 128))[t];
            int e = t * 4;
            int r = e >> 7, f = e & 127;
            hs[r][f + 0] = v.x; hs[r][f + 1] = v.y;
            hs[r][f + 2] = v.z; hs[r][f + 3] = v.w;
        }
        __syncthreads();

        // 8x512 P-tile: thread t owns cols (2t, 2t+1) for all 8 rows
        float acc0[8], acc1[8];
        #pragma unroll
        for (int r = 0; r < 8; ++r) { acc0[r] = 0.f; acc1[r] = 0.f; }
        const float2* Wf = (const float2*)W;
        for (int f = 0; f < 128; ++f) {
            float2 wp = Wf[f * 256 + t];
            #pragma unroll
            for (int r = 0; r < 8; ++r) {
                float hv = hs[r][f];
                acc0[r] = fmaf(hv, wp.x, acc0[r]);
                acc1[r] = fmaf(hv, wp.y, acc1[r]);
            }
        }
        // scatter into node-major tile: node = 8r + (2t)>>6, o = (2t)&63
        {
            const int ns = t >> 5;
            const int o = (2 * t) & 63;
            #pragma unroll
            for (int r = 0; r < 8; ++r) {
                *(float2*)&ldsA[r * 8 + ns][o] = make_float2(acc0[r], acc1[r]);
            }
        }
        __syncthreads();

        // src/tgt projections
        {
            const int r = t & 63, og = t >> 6;
            float sdot = 0.f, gdot = 0.f;
            #pragma unroll
            for (int k = 0; k < 16; ++k) {
                int o = og * 16 + k;
                float hv = ldsA[r][o];
                sdot = fmaf(hv, aW[hd * 128 + o], sdot);
                gdot = fmaf(hv, aW[hd * 128 + 64 + o], gdot);
            }
            redS[og][r] = sdot; redT[og][r] = gdot;
        }
        __syncthreads();
        if (t < 64) {
            float sp = (redS[0][t] + redS[1][t] + redS[2][t] + redS[3][t]) * LOG2E;
            ess[hd * 8192 + m0 + t]        = exp2_fast(sp);
            ess[hd * 8192 + 4096 + m0 + t] = exp2_fast(0.2f * sp);
        } else if (t < 128) {
            int r = t - 64;
            float tv = (redT[0][r] + redT[1][r] + redT[2][r] + redT[3][r]) * LOG2E;
            ets[hd * 8192 + m0 + r]        = exp2_fast(tv);
            ets[hd * 8192 + 4096 + m0 + r] = exp2_fast(0.2f * tv);
        }

        // bf16 k-tiled transpose out (reads ldsA, stable since last barrier)
        unsigned short* d = htT2 + (hd * 128 + (m0 >> 5)) * 2048;
        #pragma unroll
        for (int i = 0; i < 16; ++i) {
            int id = t + 256 * i;
            int mi = id & 31, o = (id >> 5) & 63, ct = id >> 11;
            d[ct * 2048 + o * 32 + mi] = f2bf(ldsA[mi + 32 * ct][o]);
        }
    }
}

// ---------------------------------------------------------------------------
// Kernel 2 v8: fused GAT attention, select-free inner loop.
// grid 1024 x 256: block = (head = bid&7 -> XCD-pinned, s32 = bid>>3).
// 4 waves = 4 k-quarters; wave: 32 rows (2 g2) x 32 c-iters.
// Weights via max-of-products (exp/max commute):
//   w(r,c) = mask & bf16(max(es_r*et_c, es2_r*et2_c))
// Per pair: 2 v_pk_mul_f32 + 2 v_max + 1 cvt_pk + ~4 mask ops. No cmp,
// no cndmask, no vcc serialization, no transcendentals.
// LDS: 32 KB SoA et/et2 tables (quad-broadcast reads); comb unions after.
// pd via ones-A MFMA. Bitmask words direct from global (L2-resident).
// ---------------------------------------------------------------------------
__global__ void __launch_bounds__(256, 4) k_attn(const unsigned int* __restrict__ abm,
                                                 const unsigned short* __restrict__ htT2,
                                                 const float* __restrict__ ess,
                                                 const float* __restrict__ ets,
                                                 float* __restrict__ out) {
    __shared__ __align__(16) float smem[8192];    // 32 KB: et|et2 -> comb union

    const int t = threadIdx.x;
    const int kq = t >> 6;
    const int lane = t & 63;
    const int li = lane & 15;
    const int quad = lane >> 4;
    const int head = blockIdx.x & 7;
    const int s32 = blockIdx.x >> 3;         // 0..127
    const int s64 = s32 >> 1, half = s32 & 1;
    const int i0 = s32 * 32;

    // phase 0: stage SoA et/et2 head-slice (32 KB, contiguous copy)
    {
        const float4* esrc = (const float4*)(ets + head * 8192);
        float4* edst = (float4*)smem;
        #pragma unroll
        for (int i = 0; i < 8; ++i) edst[t + 256 * i] = esrc[t + 256 * i];
    }

    // per-row constants (table lookups, no exp)
    f32x2 esv[2], es2v[2];
    #pragma unroll
    for (int g2 = 0; g2 < 2; ++g2) {
        float e1 = ess[head * 8192 + i0 + 16 * g2 + li];
        float e2 = ess[head * 8192 + 4096 + i0 + 16 * g2 + li];
        esv[g2]  = (f32x2){e1, e1};
        es2v[g2] = (f32x2){e2, e2};
    }

    f32x4 acc[8];
    #pragma unroll
    for (int i = 0; i < 8; ++i) acc[i] = (f32x4){0.f, 0.f, 0.f, 0.f};
    f32x4 apd[2];
    apd[0] = (f32x4){0.f, 0.f, 0.f, 0.f};
    apd[1] = (f32x4){0.f, 0.f, 0.f, 0.f};

    const uint4 onesw = {0x3F803F80u, 0x3F803F80u, 0x3F803F80u, 0x3F803F80u};
    const bf16x8 aones = __builtin_bit_cast(bf16x8, onesw);

    const uint4* ap = (const uint4*)(htT2 + head * HT_STRIDE) + (li * 4 + quad);
    const unsigned int* bmp = abm + s64 * 8192 + half * 2 + li * 4;

    __syncthreads();

    const int c0 = kq * 32;
    #pragma unroll 1
    for (int ci = 0; ci < 32; ++ci) {
        const int c = c0 + ci;
        uint4 av0 = ap[c * 256 + 0];
        uint4 av1 = ap[c * 256 + 64];
        uint4 av2 = ap[c * 256 + 128];
        uint4 av3 = ap[c * 256 + 192];
        uint2 bw = *(const uint2*)(bmp + c * 64);     // L2-resident bitwords

        // SoA et/et2 for this quad's 8 cols (LDS broadcast, pk-adjacent)
        const float4* etp  = (const float4*)(smem + c * 32 + quad * 8);
        const float4* et2p = (const float4*)(smem + 4096 + c * 32 + quad * 8);
        float4 ta = etp[0],  tb = etp[1];
        float4 ua = et2p[0], ub = et2p[1];
        const f32x2 etq[4]  = {(f32x2){ta.x, ta.y}, (f32x2){ta.z, ta.w},
                               (f32x2){tb.x, tb.y}, (f32x2){tb.z, tb.w}};
        const f32x2 et2q[4] = {(f32x2){ua.x, ua.y}, (f32x2){ua.z, ua.w},
                               (f32x2){ub.x, ub.y}, (f32x2){ub.z, ub.w}};

        const unsigned int wb[2] = {bw.x, bw.y};
        #pragma unroll
        for (int g2 = 0; g2 < 2; ++g2) {
            const unsigned int wq = wb[g2] >> (quad * 8);
            unsigned int pk[4];
            #pragma unroll
            for (int m = 0; m < 4; ++m) {
                f32x2 p1 = etq[m] * esv[g2];          // v_pk_mul_f32
                f32x2 p2 = et2q[m] * es2v[g2];        // v_pk_mul_f32
                float w0 = fmaxf(p1[0], p2[0]);
                float w1 = fmaxf(p1[1], p2[1]);
                unsigned int pkm;
                asm("v_cvt_pk_bf16_f32 %0, %1, %2" : "=v"(pkm) : "v"(w0), "v"(w1));
                // halfword mask from adjacency bits (sbfe-shaped)
                const int j0 = 2 * m, j1 = 2 * m + 1;
                const unsigned int lo = (unsigned int)((int)(wq << (31 - j0)) >> 31);
                const unsigned int hi = (unsigned int)((int)(wq << (31 - j1)) >> 31);
                pk[m] = pkm & ((lo & 0x0000FFFFu) | (hi & 0xFFFF0000u));
            }
            uint4 bv; bv.x = pk[0]; bv.y = pk[1]; bv.z = pk[2]; bv.w = pk[3];
            bf16x8 bfrag = __builtin_bit_cast(bf16x8, bv);
            apd[g2] = __builtin_amdgcn_mfma_f32_16x16x32_bf16(aones, bfrag, apd[g2], 0, 0, 0);
            acc[g2 * 4 + 0] = __builtin_amdgcn_mfma_f32_16x16x32_bf16(__builtin_bit_cast(bf16x8, av0), bfrag, acc[g2 * 4 + 0], 0, 0, 0);
            acc[g2 * 4 + 1] = __builtin_amdgcn_mfma_f32_16x16x32_bf16(__builtin_bit_cast(bf16x8, av1), bfrag, acc[g2 * 4 + 1], 0, 0, 0);
            acc[g2 * 4 + 2] = __builtin_amdgcn_mfma_f32_16x16x32_bf16(__builtin_bit_cast(bf16x8, av2), bfrag, acc[g2 * 4 + 2], 0, 0, 0);
            acc[g2 * 4 + 3] = __builtin_amdgcn_mfma_f32_16x16x32_bf16(__builtin_bit_cast(bf16x8, av3), bfrag, acc[g2 * 4 + 3], 0, 0, 0);
        }
    }

    // ---- phase 3: combine 4 k-quarters, denominator, store ----
    __syncthreads();             // all waves done with et tables before overwrite
    if (kq != 0) {
        float* cb = smem + ((kq - 1) * 64 + lane) * 36;  // 144 B stride, 16B-aligned
        #pragma unroll
        for (int i = 0; i < 8; ++i) ((f32x4*)cb)[i] = acc[i];
        cb[32] = apd[0][0]; cb[33] = apd[1][0];
    }
    __syncthreads();
    if (kq == 0) {
        float pd[2] = {apd[0][0], apd[1][0]};
        #pragma unroll
        for (int q = 0; q < 3; ++q) {
            const float* cb = smem + (q * 64 + lane) * 36;
            #pragma unroll
            for (int i = 0; i < 8; ++i) acc[i] += ((const f32x4*)cb)[i];
            pd[0] += cb[32]; pd[1] += cb[33];
        }
        #pragma unroll
        for (int g2 = 0; g2 < 2; ++g2) {
            const float rd = 1.0f / pd[g2];   // ones-MFMA already summed quads
            float4* op = (float4*)(out + head * HT_STRIDE + (i0 + 16 * g2 + li) * 64);
            #pragma unroll
            for (int f = 0; f < 4; ++f) {
                f32x4 a = acc[g2 * 4 + f];
                op[f * 4 + quad] = make_float4(a[0] * rd, a[1] * rd, a[2] * rd, a[3] * rd);
            }
        }
    }
}

extern "C" void kernel_launch(void* const* d_in, const int* in_sizes, int n_in,
                              void* d_out, int out_size, void* d_ws, size_t ws_size,
                              hipStream_t stream) {
    const float* h   = (const float*)d_in[0];  // (1,4096,128) f32
    const int*   adj = (const int*)d_in[1];    // (4096,4096) i32
    const float* W   = (const float*)d_in[2];  // (128,512) f32
    const float* aW  = (const float*)d_in[3];  // (8,128,1) f32
    float* out = (float*)d_out;                // (1,8,4096,64) f32

    // ws layout (6.5 MB): ess(256K) | ets(256K) | abm(2MB) | htT2(4MB)
    char* ws = (char*)d_ws;
    float* ess = (float*)(ws);
    float* ets = (float*)(ws + 262144);
    unsigned int*   abm  = (unsigned int*)(ws + 524288);
    unsigned short* htT2 = (unsigned short*)(ws + 2621440);

    hipLaunchKernelGGL(k_fused, dim3(1024), dim3(256), 0, stream,
                       h, adj, W, aW, ess, ets, htT2, abm);
    hipLaunchKernelGGL(k_attn,  dim3(1024), dim3(256), 0, stream,
                       abm, htT2, ess, ets, out);
}